// Round 1
// baseline (399.007 us; speedup 1.0000x reference)
//
#include <hip/hip_runtime.h>
#include <hip/hip_bf16.h>
#include <stdint.h>

typedef unsigned short ushort_t;
typedef __attribute__((ext_vector_type(8))) short short8;
typedef __attribute__((ext_vector_type(4))) float floatx4;

#define DEV __device__ __forceinline__

// fp32 -> bf16 round-to-nearest-even (bit trick, no NaN inputs here)
DEV ushort_t f2b(float f) {
  uint32_t x = __float_as_uint(f);
  uint32_t r = (x + 0x7FFFu + ((x >> 16) & 1u)) >> 16;
  return (ushort_t)r;
}
DEV float dot2bf(uint32_t a, uint32_t b) {
  float alo = __uint_as_float(a << 16), ahi = __uint_as_float(a & 0xFFFF0000u);
  float blo = __uint_as_float(b << 16), bhi = __uint_as_float(b & 0xFFFF0000u);
  return alo * blo + ahi * bhi;
}

DEV void async16(const ushort_t* g, ushort_t* l) {
  __builtin_amdgcn_global_load_lds(
      (const __attribute__((address_space(1))) void*)g,
      (__attribute__((address_space(3))) void*)l, 16, 0, 0);
}

// ---------------- fp32 -> bf16 conversion (vectorized, grid-stride) ----------
__global__ void cvt4(const float4* __restrict__ src, ushort4* __restrict__ dst, int n4) {
  int i = blockIdx.x * blockDim.x + threadIdx.x;
  int st = gridDim.x * blockDim.x;
  for (; i < n4; i += st) {
    float4 v = src[i];
    dst[i] = make_ushort4(f2b(v.x), f2b(v.y), f2b(v.z), f2b(v.w));
  }
}

// ---------------- bf16 GEMM: C[M,N] = A[M,K] * B[N,K]^T ---------------------
// 128x128 block tile, 256 threads (4 waves, 2x2), each wave 64x64 (4x4 MFMA
// 16x16x32 tiles). global_load_lds width=16 staging, BK=32, 2-barrier K-loop.
// MODE 0: outB = bf16(acc)                         (QKV)
// MODE 1: outF = 2*acc; outB = bf16(2*acc)         (mid = attn_out+attn_out)
// MODE 2: outB = bf16(relu(acc + bias[n]))         (MLP hidden)
// MODE 3: outF = acc + bias[n] + addF[m,n]         (final output, fp32)
template <int MODE>
__launch_bounds__(256)
__global__ void gemm_bt(const ushort_t* __restrict__ A, const ushort_t* __restrict__ Bm,
                        int M, int N, int K,
                        ushort_t* __restrict__ outB, float* __restrict__ outF,
                        const float* __restrict__ bias, const float* __restrict__ addF) {
  __shared__ alignas(16) ushort_t As[128 * 32];
  __shared__ alignas(16) ushort_t Bs[128 * 32];
  const int tid = threadIdx.x;
  const int wave = tid >> 6, lane = tid & 63;
  const int wm = wave >> 1, wn = wave & 1;
  const int m0 = blockIdx.y * 128, n0 = blockIdx.x * 128;

  floatx4 acc[4][4];
#pragma unroll
  for (int i = 0; i < 4; i++)
#pragma unroll
    for (int j = 0; j < 4; j++) acc[i][j] = (floatx4){0.f, 0.f, 0.f, 0.f};

  // staging: wave w covers 32 rows of As/Bs via two 1KB global_load_lds.
  // lane l -> row = base + l/4, kcol = (l%4)*8  (16B per lane)
  const int srow = wave * 32 + (lane >> 2);
  const int scol = (lane & 3) * 8;
  const ushort_t* gA0 = A + (size_t)(m0 + srow) * K + scol;
  const ushort_t* gA1 = gA0 + (size_t)16 * K;
  const ushort_t* gB0 = Bm + (size_t)(n0 + srow) * K + scol;
  const ushort_t* gB1 = gB0 + (size_t)16 * K;
  ushort_t* lA0 = As + wave * 1024;
  ushort_t* lA1 = As + wave * 1024 + 512;
  ushort_t* lB0 = Bs + wave * 1024;
  ushort_t* lB1 = Bs + wave * 1024 + 512;

  const int fr = lane & 15, fq = lane >> 4;
  const ushort_t* rdA = As + (wm * 64 + fr) * 32 + fq * 8;
  const ushort_t* rdB = Bs + (wn * 64 + fr) * 32 + fq * 8;

  for (int k0 = 0; k0 < K; k0 += 32) {
    async16(gA0, lA0);
    async16(gA1, lA1);
    async16(gB0, lB0);
    async16(gB1, lB1);
    gA0 += 32; gA1 += 32; gB0 += 32; gB1 += 32;
    __syncthreads();  // drains vmcnt -> staged data visible
    short8 af[4], bfv[4];
#pragma unroll
    for (int mt = 0; mt < 4; mt++) af[mt] = *(const short8*)(rdA + mt * 16 * 32);
#pragma unroll
    for (int nt = 0; nt < 4; nt++) bfv[nt] = *(const short8*)(rdB + nt * 16 * 32);
#pragma unroll
    for (int mt = 0; mt < 4; mt++)
#pragma unroll
      for (int nt = 0; nt < 4; nt++)
        acc[mt][nt] = __builtin_amdgcn_mfma_f32_16x16x32_bf16(af[mt], bfv[nt], acc[mt][nt], 0, 0, 0);
    __syncthreads();  // protect LDS before next stage
  }

  // C/D layout: col = lane&15, row = (lane>>4)*4 + reg   [m89-verified]
  const int crow = m0 + wm * 64 + (lane >> 4) * 4;
  const int ccol = n0 + wn * 64 + (lane & 15);
#pragma unroll
  for (int mt = 0; mt < 4; mt++)
#pragma unroll
    for (int nt = 0; nt < 4; nt++) {
      floatx4 a = acc[mt][nt];
#pragma unroll
      for (int r = 0; r < 4; r++) {
        const int gm = crow + mt * 16 + r;
        const int gn = ccol + nt * 16;
        const size_t idx = (size_t)gm * N + gn;
        float v = a[r];
        if constexpr (MODE == 0) {
          outB[idx] = f2b(v);
        } else if constexpr (MODE == 1) {
          float t = 2.f * v;
          outF[idx] = t;
          outB[idx] = f2b(t);
        } else if constexpr (MODE == 2) {
          float t = v + bias[gn];
          t = t > 0.f ? t : 0.f;
          outB[idx] = f2b(t);
        } else {
          outF[idx] = v + bias[gn] + addF[idx];
        }
      }
    }
}

// ---------------- attention (degenerate mask -> diag + suffix sum) ----------
// Reference mask keeps: p<q -> -1e10 (weight 0), p==q -> score, p>q -> logit 0.
// z[q] = (e_q * v[q] + sum_{p>q} v[p]) / (e_q + (S-1-q)),  e_q = exp(q_q.k_q/8)
// grid = B*H blocks, 1024 threads: 16 s-chunks x 64 head-dims.
__launch_bounds__(1024)
__global__ void attn_diag(const ushort_t* __restrict__ qkv, ushort_t* __restrict__ Z) {
  const int b = blockIdx.x >> 4;
  const int i = blockIdx.x & 15;
  __shared__ float eS[2048];
  __shared__ float psum[16][64];
  const int t = threadIdx.x;
  const size_t rowbase = (size_t)b * 2048 * 3072;
  const int qoff = i * 64, koff = 1024 + i * 64, voff = 2048 + i * 64;

  // phase 0: e[s] = exp(diag score / 8)
  for (int s = t; s < 2048; s += 1024) {
    const uint4* qp = (const uint4*)(qkv + rowbase + (size_t)s * 3072 + qoff);
    const uint4* kp = (const uint4*)(qkv + rowbase + (size_t)s * 3072 + koff);
    float d = 0.f;
#pragma unroll
    for (int j = 0; j < 8; j++) {
      uint4 qa = qp[j], ka = kp[j];
      d += dot2bf(qa.x, ka.x) + dot2bf(qa.y, ka.y) + dot2bf(qa.z, ka.z) + dot2bf(qa.w, ka.w);
    }
    eS[s] = __expf(d * 0.125f);
  }

  // phase 1: per-chunk partial sums of v
  const int c = t >> 6;   // chunk 0..15 (128 s each)
  const int h = t & 63;   // head dim
  const int s0 = c * 128, s1 = s0 + 128;
  float lsum = 0.f;
  for (int s = s0; s < s1; s++)
    lsum += __uint_as_float(((uint32_t)qkv[rowbase + (size_t)s * 3072 + voff + h]) << 16);
  psum[c][h] = lsum;
  __syncthreads();

  float suff = 0.f;
  for (int cc = c + 1; cc < 16; cc++) suff += psum[cc][h];

  // phase 2: backward walk within chunk, emit z
  float running = suff;  // = sum_{p > s} v[p] at loop entry for s = s1-1
  for (int s = s1 - 1; s >= s0; s--) {
    float vv = __uint_as_float(((uint32_t)qkv[rowbase + (size_t)s * 3072 + voff + h]) << 16);
    float e = eS[s];
    float z = (e * vv + running) / (e + (float)(2047 - s));
    Z[((size_t)b * 2048 + s) * 1024 + i * 64 + h] = f2b(z);
    running += vv;
  }
}

// ---------------- launch ----------------------------------------------------
extern "C" void kernel_launch(void* const* d_in, const int* in_sizes, int n_in,
                              void* d_out, int out_size, void* d_ws, size_t ws_size,
                              hipStream_t stream) {
  const float* x     = (const float*)d_in[0];
  const float* W_Q   = (const float*)d_in[1];
  const float* W_K   = (const float*)d_in[2];
  const float* W_V   = (const float*)d_in[3];
  const float* W_O   = (const float*)d_in[4];
  const float* W_in  = (const float*)d_in[5];
  const float* b_in  = (const float*)d_in[6];
  const float* W_out = (const float*)d_in[7];
  const float* b_out = (const float*)d_in[8];
  float* out = (float*)d_out;

  char* ws = (char*)d_ws;
  ushort_t* Xb    = (ushort_t*)ws;  ws += (size_t)4194304 * 2;   // x bf16 [4096,1024]
  ushort_t* Wqkv  = (ushort_t*)ws;  ws += (size_t)3145728 * 2;   // [3072,1024]
  ushort_t* WOb   = (ushort_t*)ws;  ws += (size_t)1048576 * 2;   // [1024,1024]
  ushort_t* Winb  = (ushort_t*)ws;  ws += (size_t)4194304 * 2;   // [4096,1024]
  ushort_t* Woutb = (ushort_t*)ws;  ws += (size_t)4194304 * 2;   // [1024,4096]
  ushort_t* QKV   = (ushort_t*)ws;  ws += (size_t)12582912 * 2;  // [4096,3072]
  ushort_t* Z     = (ushort_t*)ws;  ws += (size_t)4194304 * 2;   // [4096,1024]
  ushort_t* midb  = (ushort_t*)ws;  ws += (size_t)4194304 * 2;   // [4096,1024]
  float*    midf  = (float*)ws;     ws += (size_t)4194304 * 4;   // [4096,1024]
  ushort_t* Hb    = (ushort_t*)ws;  ws += (size_t)16777216 * 2;  // [4096,4096]

  auto cvt = [&](const float* s, ushort_t* d, size_t n) {
    int n4 = (int)(n / 4);
    int blocks = (n4 + 255) / 256;
    if (blocks > 2048) blocks = 2048;
    cvt4<<<dim3(blocks), dim3(256), 0, stream>>>((const float4*)s, (ushort4*)d, n4);
  };
  cvt(x, Xb, 4194304);
  cvt(W_Q, Wqkv, 1048576);
  cvt(W_K, Wqkv + 1048576, 1048576);
  cvt(W_V, Wqkv + 2097152, 1048576);
  cvt(W_O, WOb, 1048576);
  cvt(W_in, Winb, 4194304);
  cvt(W_out, Woutb, 4194304);

  // QKV = X * Wqkv^T   [4096, 3072]
  gemm_bt<0><<<dim3(24, 32), 256, 0, stream>>>(Xb, Wqkv, 4096, 3072, 1024,
                                               QKV, nullptr, nullptr, nullptr);
  // attention -> Z [4096, 1024] bf16
  attn_diag<<<32, 1024, 0, stream>>>(QKV, Z);
  // mid = 2 * (Z * W_O^T)  -> midf (fp32) + midb (bf16)
  gemm_bt<1><<<dim3(8, 32), 256, 0, stream>>>(Z, WOb, 4096, 1024, 1024,
                                              midb, midf, nullptr, nullptr);
  // H = relu(mid * W_in^T + b_in) [4096, 4096] bf16
  gemm_bt<2><<<dim3(32, 32), 256, 0, stream>>>(midb, Winb, 4096, 4096, 1024,
                                               Hb, nullptr, b_in, nullptr);
  // out = mid + H * W_out^T + b_out  [4096, 1024] fp32
  gemm_bt<3><<<dim3(8, 32), 256, 0, stream>>>(Hb, Woutb, 4096, 1024, 4096,
                                              nullptr, out, b_out, midf);
}

// Round 2
// 354.023 us; speedup vs baseline: 1.1271x; 1.1271x over previous
//
#include <hip/hip_runtime.h>
#include <hip/hip_bf16.h>
#include <stdint.h>

typedef unsigned short ushort_t;
typedef __attribute__((ext_vector_type(8))) short short8;
typedef __attribute__((ext_vector_type(4))) float floatx4;

#define DEV __device__ __forceinline__

DEV ushort_t f2b(float f) {
  uint32_t x = __float_as_uint(f);
  uint32_t r = (x + 0x7FFFu + ((x >> 16) & 1u)) >> 16;
  return (ushort_t)r;
}
DEV float b2f(ushort_t u) { return __uint_as_float(((uint32_t)u) << 16); }

DEV void async16(const ushort_t* g, ushort_t* l) {
  __builtin_amdgcn_global_load_lds(
      (const __attribute__((address_space(1))) void*)g,
      (__attribute__((address_space(3))) void*)l, 16, 0, 0);
}

// ---------------- fused fp32 -> bf16 conversion (one launch) ----------------
struct Cvt7 {
  const float* src[7];
  ushort_t* dst[7];
  unsigned start[8];  // prefix, in float4 units
};
__global__ void cvt_all(Cvt7 a) {
  unsigned idx = blockIdx.x * blockDim.x + threadIdx.x;
  if (idx >= a.start[7]) return;
  int seg = 0;
#pragma unroll
  for (int j = 1; j < 7; j++) seg += (idx >= a.start[j]) ? 1 : 0;
  unsigned off = idx - a.start[seg];
  float4 v = ((const float4*)a.src[seg])[off];
  ((ushort4*)a.dst[seg])[off] = make_ushort4(f2b(v.x), f2b(v.y), f2b(v.z), f2b(v.w));
}

// ---------------- bf16 GEMM: C[M,N] = A[M,K] * B[N,K]^T ---------------------
// 128x128 tile, 256 thr (4 waves 2x2), wave 64x64 = 4x4 MFMA 16x16x32.
// XOR-swizzled LDS k-blocks: LDS[row][p] holds global k-block p ^ ((row>>1)&3)
// -> fragment ds_read_b128s hit 8 distinct 16B superbanks per 8-lane phase.
// Swizzle applied on the GLOBAL side of global_load_lds (LDS dst must stay
// lane-contiguous); permutation stays within each row's 64B -> coalescing ok.
// MODE 0: outB = bf16(acc)                         (QKV)
// MODE 1: outB = bf16(2*acc); outF = 2*acc + bias  (mid; outF seeds d_out)
// MODE 2: outB = bf16(relu(acc + bias[n]))         (MLP hidden)
// MODE 3: unsafeAtomicAdd(outF, acc)               (split-K MLP out)
template <int MODE>
__launch_bounds__(256)
__global__ void gemm_bt(const ushort_t* __restrict__ A, const ushort_t* __restrict__ Bm,
                        int M, int N, int K, int Ksplit,
                        ushort_t* __restrict__ outB, float* __restrict__ outF,
                        const float* __restrict__ bias) {
  __shared__ alignas(16) ushort_t As[128 * 32];
  __shared__ alignas(16) ushort_t Bs[128 * 32];
  const int tid = threadIdx.x;
  const int wave = tid >> 6, lane = tid & 63;
  const int wm = wave >> 1, wn = wave & 1;
  const int m0 = blockIdx.y * 128, n0 = blockIdx.x * 128;
  const int kz = blockIdx.z * Ksplit;

  floatx4 acc[4][4];
#pragma unroll
  for (int i = 0; i < 4; i++)
#pragma unroll
    for (int j = 0; j < 4; j++) acc[i][j] = (floatx4){0.f, 0.f, 0.f, 0.f};

  // staging: lane l -> LDS row l/4 (within wave's 32 rows), colblock l&3;
  // global k-block = (l&3) ^ ((l>>3)&3)   [= colblock ^ row-swizzle]
  const int srow = wave * 32 + (lane >> 2);
  const int scol = (((lane & 3) ^ ((lane >> 3) & 3)) * 8);
  const ushort_t* gA0 = A + (size_t)(m0 + srow) * K + kz + scol;
  const ushort_t* gA1 = gA0 + (size_t)16 * K;
  const ushort_t* gB0 = Bm + (size_t)(n0 + srow) * K + kz + scol;
  const ushort_t* gB1 = gB0 + (size_t)16 * K;
  ushort_t* lA0 = As + wave * 1024;
  ushort_t* lA1 = As + wave * 1024 + 512;
  ushort_t* lB0 = Bs + wave * 1024;
  ushort_t* lB1 = Bs + wave * 1024 + 512;

  const int fr = lane & 15, fq = lane >> 4;
  const int cb = fq ^ ((fr >> 1) & 3);  // swizzled colblock; row+16 keeps (row>>1)&3
  const ushort_t* rdA = As + (wm * 64 + fr) * 32 + cb * 8;
  const ushort_t* rdB = Bs + (wn * 64 + fr) * 32 + cb * 8;

  for (int k0 = 0; k0 < Ksplit; k0 += 32) {
    async16(gA0, lA0);
    async16(gA1, lA1);
    async16(gB0, lB0);
    async16(gB1, lB1);
    gA0 += 32; gA1 += 32; gB0 += 32; gB1 += 32;
    __syncthreads();
    short8 af[4], bfv[4];
#pragma unroll
    for (int mt = 0; mt < 4; mt++) af[mt] = *(const short8*)(rdA + mt * 16 * 32);
#pragma unroll
    for (int nt = 0; nt < 4; nt++) bfv[nt] = *(const short8*)(rdB + nt * 16 * 32);
#pragma unroll
    for (int mt = 0; mt < 4; mt++)
#pragma unroll
      for (int nt = 0; nt < 4; nt++)
        acc[mt][nt] = __builtin_amdgcn_mfma_f32_16x16x32_bf16(af[mt], bfv[nt], acc[mt][nt], 0, 0, 0);
    __syncthreads();
  }

  const int crow = m0 + wm * 64 + (lane >> 4) * 4;
  const int ccol = n0 + wn * 64 + (lane & 15);
#pragma unroll
  for (int mt = 0; mt < 4; mt++)
#pragma unroll
    for (int nt = 0; nt < 4; nt++) {
      floatx4 a = acc[mt][nt];
#pragma unroll
      for (int r = 0; r < 4; r++) {
        const int gm = crow + mt * 16 + r;
        const int gn = ccol + nt * 16;
        const size_t idx = (size_t)gm * N + gn;
        float v = a[r];
        if constexpr (MODE == 0) {
          outB[idx] = f2b(v);
        } else if constexpr (MODE == 1) {
          float t = 2.f * v;
          outB[idx] = f2b(t);
          outF[idx] = t + bias[gn];
        } else if constexpr (MODE == 2) {
          float t = v + bias[gn];
          outB[idx] = f2b(t > 0.f ? t : 0.f);
        } else {
          unsafeAtomicAdd(&outF[idx], v);
        }
      }
    }
}

// ---------------- attention (degenerate mask -> diag + suffix sum) ----------
// z[q] = (e_q*v[q] + sum_{p>q} v[p]) / (e_q + (S-1-q)), e_q = exp(q.k/8)
// Pass 1: per (b,i,chunk-of-64) compute e[s] (wave-reduced diag dot) and
//         chunk V partial sums. grid = 2*16*32 = 1024 blocks, 4 waves.
__launch_bounds__(256)
__global__ void attn1(const ushort_t* __restrict__ qkv,
                      float* __restrict__ eG, float* __restrict__ psumG) {
  const int c = blockIdx.x & 31;
  const int i = (blockIdx.x >> 5) & 15;
  const int b = blockIdx.x >> 9;
  const int t = threadIdx.x, wave = t >> 6, h = t & 63;
  const size_t rowbase = (size_t)b * 2048 * 3072;
  float vacc = 0.f;
#pragma unroll 4
  for (int r = 0; r < 16; r++) {
    const int s = c * 64 + wave * 16 + r;
    const size_t rb = rowbase + (size_t)s * 3072 + i * 64 + h;
    float q = b2f(qkv[rb]);
    float k = b2f(qkv[rb + 1024]);
    float v = b2f(qkv[rb + 2048]);
    float d = q * k;
#pragma unroll
    for (int off = 32; off > 0; off >>= 1) d += __shfl_xor(d, off, 64);
    if (h == 0) eG[((size_t)(b * 16 + i)) * 2048 + s] = __expf(d * 0.125f);
    vacc += v;
  }
  __shared__ float vs[4][64];
  vs[wave][h] = vacc;
  __syncthreads();
  if (t < 64)
    psumG[(((size_t)(b * 16 + i)) * 32 + c) * 64 + t] =
        vs[0][t] + vs[1][t] + vs[2][t] + vs[3][t];
}

// Pass 2: per (b,i,chunk) suffix-sum psums of later chunks, then backward walk
// emitting z. grid = 1024 blocks x 64 threads.
__launch_bounds__(64)
__global__ void attn2(const ushort_t* __restrict__ qkv,
                      const float* __restrict__ eG, const float* __restrict__ psumG,
                      ushort_t* __restrict__ Z) {
  const int c = blockIdx.x & 31;
  const int i = (blockIdx.x >> 5) & 15;
  const int b = blockIdx.x >> 9;
  const int h = threadIdx.x;
  const size_t rowbase = (size_t)b * 2048 * 3072;
  const size_t pbase = ((size_t)(b * 16 + i)) * 32;
  float run = 0.f;
  for (int cc = c + 1; cc < 32; cc++) run += psumG[(pbase + cc) * 64 + h];
  const size_t ebase = ((size_t)(b * 16 + i)) * 2048;
  for (int r = 63; r >= 0; r--) {
    const int s = c * 64 + r;
    float vv = b2f(qkv[rowbase + (size_t)s * 3072 + 2048 + i * 64 + h]);
    float e = eG[ebase + s];
    float z = (e * vv + run) / (e + (float)(2047 - s));
    Z[((size_t)b * 2048 + s) * 1024 + i * 64 + h] = f2b(z);
    run += vv;
  }
}

// ---------------- launch ----------------------------------------------------
extern "C" void kernel_launch(void* const* d_in, const int* in_sizes, int n_in,
                              void* d_out, int out_size, void* d_ws, size_t ws_size,
                              hipStream_t stream) {
  const float* x     = (const float*)d_in[0];
  const float* W_Q   = (const float*)d_in[1];
  const float* W_K   = (const float*)d_in[2];
  const float* W_V   = (const float*)d_in[3];
  const float* W_O   = (const float*)d_in[4];
  const float* W_in  = (const float*)d_in[5];
  const float* b_in  = (const float*)d_in[6];
  const float* W_out = (const float*)d_in[7];
  const float* b_out = (const float*)d_in[8];
  float* out = (float*)d_out;

  char* ws = (char*)d_ws;
  ushort_t* Xb    = (ushort_t*)ws;  ws += (size_t)4194304 * 2;   // x bf16 [4096,1024]
  ushort_t* Wqkv  = (ushort_t*)ws;  ws += (size_t)3145728 * 2;   // [3072,1024]
  ushort_t* WOb   = (ushort_t*)ws;  ws += (size_t)1048576 * 2;   // [1024,1024]
  ushort_t* Winb  = (ushort_t*)ws;  ws += (size_t)4194304 * 2;   // [4096,1024]
  ushort_t* Woutb = (ushort_t*)ws;  ws += (size_t)4194304 * 2;   // [1024,4096]
  ushort_t* QKV   = (ushort_t*)ws;  ws += (size_t)12582912 * 2;  // [4096,3072]
  ushort_t* Z     = (ushort_t*)ws;  ws += (size_t)4194304 * 2;   // [4096,1024]
  ushort_t* midb  = (ushort_t*)ws;  ws += (size_t)4194304 * 2;   // [4096,1024]
  ushort_t* Hb    = (ushort_t*)ws;  ws += (size_t)16777216 * 2;  // [4096,4096]
  float*    eG    = (float*)ws;     ws += (size_t)65536 * 4;     // [2,16,2048]
  float*    psumG = (float*)ws;     ws += (size_t)65536 * 4;     // [2,16,32,64]

  // one fused conversion launch (x + 6 weight tensors)
  Cvt7 ca;
  ca.src[0] = x;     ca.dst[0] = Xb;
  ca.src[1] = W_Q;   ca.dst[1] = Wqkv;
  ca.src[2] = W_K;   ca.dst[2] = Wqkv + 1048576;
  ca.src[3] = W_V;   ca.dst[3] = Wqkv + 2097152;
  ca.src[4] = W_O;   ca.dst[4] = WOb;
  ca.src[5] = W_in;  ca.dst[5] = Winb;
  ca.src[6] = W_out; ca.dst[6] = Woutb;
  unsigned n4s[7] = {1048576, 262144, 262144, 262144, 262144, 1048576, 1048576};
  unsigned acc4 = 0;
  for (int j = 0; j < 7; j++) { ca.start[j] = acc4; acc4 += n4s[j]; }
  ca.start[7] = acc4;  // 4194304
  cvt_all<<<dim3((acc4 + 255) / 256), dim3(256), 0, stream>>>(ca);

  // QKV = X * Wqkv^T   [4096, 3072]
  gemm_bt<0><<<dim3(24, 32), 256, 0, stream>>>(Xb, Wqkv, 4096, 3072, 1024, 1024,
                                               QKV, nullptr, nullptr);
  // attention -> Z [4096, 1024] bf16
  attn1<<<dim3(1024), 256, 0, stream>>>(QKV, eG, psumG);
  attn2<<<dim3(1024), 64, 0, stream>>>(QKV, eG, psumG, Z);
  // mid = 2*(Z*W_O^T): midb = bf16(mid), out seeded with mid + b_out
  gemm_bt<1><<<dim3(8, 32), 256, 0, stream>>>(Z, WOb, 4096, 1024, 1024, 1024,
                                              midb, out, b_out);
  // H = relu(mid * W_in^T + b_in) [4096, 4096]
  gemm_bt<2><<<dim3(32, 32), 256, 0, stream>>>(midb, Winb, 4096, 4096, 1024, 1024,
                                               Hb, nullptr, b_in);
  // out += H * W_out^T  (split-K=4, atomic fp32 accumulate)
  gemm_bt<3><<<dim3(8, 32, 4), 256, 0, stream>>>(Hb, Woutb, 4096, 1024, 4096, 1024,
                                                 nullptr, out, nullptr);
}

// Round 3
// 340.238 us; speedup vs baseline: 1.1727x; 1.0405x over previous
//
#include <hip/hip_runtime.h>
#include <hip/hip_bf16.h>
#include <stdint.h>

typedef unsigned short ushort_t;
typedef __attribute__((ext_vector_type(8))) short short8;
typedef __attribute__((ext_vector_type(4))) float floatx4;

#define DEV __device__ __forceinline__

DEV ushort_t f2b(float f) {
  uint32_t x = __float_as_uint(f);
  uint32_t r = (x + 0x7FFFu + ((x >> 16) & 1u)) >> 16;
  return (ushort_t)r;
}
DEV float b2f(ushort_t u) { return __uint_as_float(((uint32_t)u) << 16); }

DEV void async16(const ushort_t* g, ushort_t* l) {
  __builtin_amdgcn_global_load_lds(
      (const __attribute__((address_space(1))) void*)g,
      (__attribute__((address_space(3))) void*)l, 16, 0, 0);
}

// ---------------- fused fp32 -> bf16 conversion (one launch) ----------------
struct Cvt7 {
  const float* src[7];
  ushort_t* dst[7];
  unsigned start[8];  // prefix, in float4 units
};
__global__ void cvt_all(Cvt7 a) {
  unsigned idx = blockIdx.x * blockDim.x + threadIdx.x;
  if (idx >= a.start[7]) return;
  int seg = 0;
#pragma unroll
  for (int j = 1; j < 7; j++) seg += (idx >= a.start[j]) ? 1 : 0;
  unsigned off = idx - a.start[seg];
  float4 v = ((const float4*)a.src[seg])[off];
  ((ushort4*)a.dst[seg])[off] = make_ushort4(f2b(v.x), f2b(v.y), f2b(v.z), f2b(v.w));
}

// ---------------- bf16 GEMM: C[M,N] = A[M,K] * B[N,K]^T ---------------------
// 128x128 tile, 256 thr (4 waves 2x2), wave 64x64 = 4x4 MFMA 16x16x32.
// XOR-swizzled LDS k-blocks (R2: conflicts 4.19M -> 0).
// MODE 0: outB = bf16(acc)                         (QKV)
// MODE 1: outB = bf16(2*acc); outF = 2*acc + bias  (mid; outF seeds d_out)
// MODE 2: outB = bf16(relu(acc + bias[n]))         (MLP hidden)
// MODE 3: outF[z*M*N + idx] = acc                  (split-K partials, plain stores)
template <int MODE>
__launch_bounds__(256)
__global__ void gemm_bt(const ushort_t* __restrict__ A, const ushort_t* __restrict__ Bm,
                        int M, int N, int K, int Ksplit,
                        ushort_t* __restrict__ outB, float* __restrict__ outF,
                        const float* __restrict__ bias) {
  __shared__ alignas(16) ushort_t As[128 * 32];
  __shared__ alignas(16) ushort_t Bs[128 * 32];
  const int tid = threadIdx.x;
  const int wave = tid >> 6, lane = tid & 63;
  const int wm = wave >> 1, wn = wave & 1;
  const int m0 = blockIdx.y * 128, n0 = blockIdx.x * 128;
  const int kz = blockIdx.z * Ksplit;

  floatx4 acc[4][4];
#pragma unroll
  for (int i = 0; i < 4; i++)
#pragma unroll
    for (int j = 0; j < 4; j++) acc[i][j] = (floatx4){0.f, 0.f, 0.f, 0.f};

  const int srow = wave * 32 + (lane >> 2);
  const int scol = (((lane & 3) ^ ((lane >> 3) & 3)) * 8);
  const ushort_t* gA0 = A + (size_t)(m0 + srow) * K + kz + scol;
  const ushort_t* gA1 = gA0 + (size_t)16 * K;
  const ushort_t* gB0 = Bm + (size_t)(n0 + srow) * K + kz + scol;
  const ushort_t* gB1 = gB0 + (size_t)16 * K;
  ushort_t* lA0 = As + wave * 1024;
  ushort_t* lA1 = As + wave * 1024 + 512;
  ushort_t* lB0 = Bs + wave * 1024;
  ushort_t* lB1 = Bs + wave * 1024 + 512;

  const int fr = lane & 15, fq = lane >> 4;
  const int cb = fq ^ ((fr >> 1) & 3);
  const ushort_t* rdA = As + (wm * 64 + fr) * 32 + cb * 8;
  const ushort_t* rdB = Bs + (wn * 64 + fr) * 32 + cb * 8;

  for (int k0 = 0; k0 < Ksplit; k0 += 32) {
    async16(gA0, lA0);
    async16(gA1, lA1);
    async16(gB0, lB0);
    async16(gB1, lB1);
    gA0 += 32; gA1 += 32; gB0 += 32; gB1 += 32;
    __syncthreads();
    short8 af[4], bfv[4];
#pragma unroll
    for (int mt = 0; mt < 4; mt++) af[mt] = *(const short8*)(rdA + mt * 16 * 32);
#pragma unroll
    for (int nt = 0; nt < 4; nt++) bfv[nt] = *(const short8*)(rdB + nt * 16 * 32);
#pragma unroll
    for (int mt = 0; mt < 4; mt++)
#pragma unroll
      for (int nt = 0; nt < 4; nt++)
        acc[mt][nt] = __builtin_amdgcn_mfma_f32_16x16x32_bf16(af[mt], bfv[nt], acc[mt][nt], 0, 0, 0);
    __syncthreads();
  }

  const int crow = m0 + wm * 64 + (lane >> 4) * 4;
  const int ccol = n0 + wn * 64 + (lane & 15);
  const size_t zoff = (size_t)blockIdx.z * M * N;
#pragma unroll
  for (int mt = 0; mt < 4; mt++)
#pragma unroll
    for (int nt = 0; nt < 4; nt++) {
      floatx4 a = acc[mt][nt];
#pragma unroll
      for (int r = 0; r < 4; r++) {
        const int gm = crow + mt * 16 + r;
        const int gn = ccol + nt * 16;
        const size_t idx = (size_t)gm * N + gn;
        float v = a[r];
        if constexpr (MODE == 0) {
          outB[idx] = f2b(v);
        } else if constexpr (MODE == 1) {
          float t = 2.f * v;
          outB[idx] = f2b(t);
          outF[idx] = t + bias[gn];
        } else if constexpr (MODE == 2) {
          float t = v + bias[gn];
          outB[idx] = f2b(t > 0.f ? t : 0.f);
        } else {
          outF[zoff + idx] = v;
        }
      }
    }
}

// ---------------- split-K reduction: out += P0+P1+P2+P3 ---------------------
__launch_bounds__(256)
__global__ void reduce4(const float4* __restrict__ P, float4* __restrict__ out, int n4) {
  int i = blockIdx.x * blockDim.x + threadIdx.x;
  int st = gridDim.x * blockDim.x;
  for (; i < n4; i += st) {
    float4 a = out[i];
    float4 p0 = P[i], p1 = P[i + 1048576], p2 = P[i + 2097152], p3 = P[i + 3145728];
    a.x += p0.x + p1.x + p2.x + p3.x;
    a.y += p0.y + p1.y + p2.y + p3.y;
    a.z += p0.z + p1.z + p2.z + p3.z;
    a.w += p0.w + p1.w + p2.w + p3.w;
    out[i] = a;
  }
}

// ---------------- attention (degenerate mask -> diag + suffix sum) ----------
// z[q] = (e_q*v[q] + sum_{p>q} v[p]) / (e_q + (S-1-q)), e_q = exp(q.k/8)
__launch_bounds__(256)
__global__ void attn1(const ushort_t* __restrict__ qkv,
                      float* __restrict__ eG, float* __restrict__ psumG) {
  const int c = blockIdx.x & 31;
  const int i = (blockIdx.x >> 5) & 15;
  const int b = blockIdx.x >> 9;
  const int t = threadIdx.x, wave = t >> 6, h = t & 63;
  const size_t rowbase = (size_t)b * 2048 * 3072;
  float vacc = 0.f;
#pragma unroll 4
  for (int r = 0; r < 16; r++) {
    const int s = c * 64 + wave * 16 + r;
    const size_t rb = rowbase + (size_t)s * 3072 + i * 64 + h;
    float q = b2f(qkv[rb]);
    float k = b2f(qkv[rb + 1024]);
    float v = b2f(qkv[rb + 2048]);
    float d = q * k;
#pragma unroll
    for (int off = 32; off > 0; off >>= 1) d += __shfl_xor(d, off, 64);
    if (h == 0) eG[((size_t)(b * 16 + i)) * 2048 + s] = __expf(d * 0.125f);
    vacc += v;
  }
  __shared__ float vs[4][64];
  vs[wave][h] = vacc;
  __syncthreads();
  if (t < 64)
    psumG[(((size_t)(b * 16 + i)) * 32 + c) * 64 + t] =
        vs[0][t] + vs[1][t] + vs[2][t] + vs[3][t];
}

// Pass 2: 256 blocks x 256 thr; each wave owns one 64-s chunk. Loads batched
// 16-deep (independent of the serial `run` chain) for latency hiding.
__launch_bounds__(256)
__global__ void attn2(const ushort_t* __restrict__ qkv,
                      const float* __restrict__ eG, const float* __restrict__ psumG,
                      ushort_t* __restrict__ Z) {
  const int wave = threadIdx.x >> 6, h = threadIdx.x & 63;
  const int c = (blockIdx.x & 7) * 4 + wave;
  const int i = (blockIdx.x >> 3) & 15;
  const int b = blockIdx.x >> 7;
  const size_t rowbase = (size_t)b * 2048 * 3072;
  const size_t pbase = ((size_t)(b * 16 + i)) * 32;
  float run = 0.f;
#pragma unroll 8
  for (int cc = c + 1; cc < 32; cc++) run += psumG[(pbase + cc) * 64 + h];
  const size_t ebase = ((size_t)(b * 16 + i)) * 2048;
  for (int t4 = 3; t4 >= 0; t4--) {
    float vv[16], ee[16];
#pragma unroll
    for (int j = 0; j < 16; j++) {
      const int s = c * 64 + t4 * 16 + j;
      vv[j] = b2f(qkv[rowbase + (size_t)s * 3072 + 2048 + i * 64 + h]);
      ee[j] = eG[ebase + s];
    }
#pragma unroll
    for (int j = 15; j >= 0; j--) {
      const int s = c * 64 + t4 * 16 + j;
      float z = (ee[j] * vv[j] + run) / (ee[j] + (float)(2047 - s));
      Z[((size_t)b * 2048 + s) * 1024 + i * 64 + h] = f2b(z);
      run += vv[j];
    }
  }
}

// ---------------- launch ----------------------------------------------------
extern "C" void kernel_launch(void* const* d_in, const int* in_sizes, int n_in,
                              void* d_out, int out_size, void* d_ws, size_t ws_size,
                              hipStream_t stream) {
  const float* x     = (const float*)d_in[0];
  const float* W_Q   = (const float*)d_in[1];
  const float* W_K   = (const float*)d_in[2];
  const float* W_V   = (const float*)d_in[3];
  const float* W_O   = (const float*)d_in[4];
  const float* W_in  = (const float*)d_in[5];
  const float* b_in  = (const float*)d_in[6];
  const float* W_out = (const float*)d_in[7];
  const float* b_out = (const float*)d_in[8];
  float* out = (float*)d_out;

  // ws layout (104.5 MB). P (64 MB split-K partials) aliases the front region,
  // all of which is dead by the time MODE 3 launches:
  //   Xb, Wqkv dead after QKV gemm; WOb, Z dead after MODE1; QKV dead after
  //   attn2; midb, Winb dead after MODE2 (MODE2 is the last consumer).
  char* base = (char*)d_ws;
  const size_t MB = 1048576;
  ushort_t* Xb    = (ushort_t*)(base + 0 * MB);    // 8 MB  [0,8)
  ushort_t* Wqkv  = (ushort_t*)(base + 8 * MB);    // 6 MB  [8,14)
  ushort_t* WOb   = (ushort_t*)(base + 14 * MB);   // 2 MB  [14,16)
  ushort_t* Z     = (ushort_t*)(base + 16 * MB);   // 8 MB  [16,24)
  ushort_t* QKV   = (ushort_t*)(base + 24 * MB);   // 24 MB [24,48)
  ushort_t* midb  = (ushort_t*)(base + 48 * MB);   // 8 MB  [48,56)
  ushort_t* Winb  = (ushort_t*)(base + 56 * MB);   // 8 MB  [56,64)
  float*    P     = (float*)(base + 0 * MB);       // 64 MB [0,64)   (alias)
  ushort_t* Woutb = (ushort_t*)(base + 64 * MB);   // 8 MB  [64,72)
  ushort_t* Hb    = (ushort_t*)(base + 72 * MB);   // 32 MB [72,104)
  float*    eG    = (float*)(base + 104 * MB);           // 256 KB
  float*    psumG = (float*)(base + 104 * MB + 262144);  // 256 KB

  Cvt7 ca;
  ca.src[0] = x;     ca.dst[0] = Xb;
  ca.src[1] = W_Q;   ca.dst[1] = Wqkv;
  ca.src[2] = W_K;   ca.dst[2] = Wqkv + 1048576;
  ca.src[3] = W_V;   ca.dst[3] = Wqkv + 2097152;
  ca.src[4] = W_O;   ca.dst[4] = WOb;
  ca.src[5] = W_in;  ca.dst[5] = Winb;
  ca.src[6] = W_out; ca.dst[6] = Woutb;
  unsigned n4s[7] = {1048576, 262144, 262144, 262144, 262144, 1048576, 1048576};
  unsigned acc4 = 0;
  for (int j = 0; j < 7; j++) { ca.start[j] = acc4; acc4 += n4s[j]; }
  ca.start[7] = acc4;
  cvt_all<<<dim3((acc4 + 255) / 256), dim3(256), 0, stream>>>(ca);

  // QKV = X * Wqkv^T   [4096, 3072]
  gemm_bt<0><<<dim3(24, 32), 256, 0, stream>>>(Xb, Wqkv, 4096, 3072, 1024, 1024,
                                               QKV, nullptr, nullptr);
  // attention -> Z [4096, 1024] bf16
  attn1<<<dim3(1024), 256, 0, stream>>>(QKV, eG, psumG);
  attn2<<<dim3(256), 256, 0, stream>>>(QKV, eG, psumG, Z);
  // mid = 2*(Z*W_O^T): midb = bf16(mid), out seeded with mid + b_out
  gemm_bt<1><<<dim3(8, 32), 256, 0, stream>>>(Z, WOb, 4096, 1024, 1024, 1024,
                                              midb, out, b_out);
  // H = relu(mid * W_in^T + b_in) [4096, 4096]
  gemm_bt<2><<<dim3(32, 32), 256, 0, stream>>>(midb, Winb, 4096, 4096, 1024, 1024,
                                               Hb, nullptr, b_in);
  // P[z] = H * W_out^T over K-slice z  (plain fp32 stores, no atomics)
  gemm_bt<3><<<dim3(8, 32, 4), 256, 0, stream>>>(Hb, Woutb, 4096, 1024, 4096, 1024,
                                                 nullptr, P, nullptr);
  // out += P0+P1+P2+P3
  reduce4<<<dim3(1024), 256, 0, stream>>>((const float4*)P, (float4*)out, 1048576);
}

// Round 4
// 327.519 us; speedup vs baseline: 1.2183x; 1.0388x over previous
//
#include <hip/hip_runtime.h>
#include <hip/hip_bf16.h>
#include <stdint.h>

typedef unsigned short ushort_t;
typedef __attribute__((ext_vector_type(8))) short short8;
typedef __attribute__((ext_vector_type(4))) float floatx4;

#define DEV __device__ __forceinline__

DEV ushort_t f2b(float f) {
  uint32_t x = __float_as_uint(f);
  uint32_t r = (x + 0x7FFFu + ((x >> 16) & 1u)) >> 16;
  return (ushort_t)r;
}
DEV float b2f(ushort_t u) { return __uint_as_float(((uint32_t)u) << 16); }

DEV void async16(const ushort_t* g, ushort_t* l) {
  __builtin_amdgcn_global_load_lds(
      (const __attribute__((address_space(1))) void*)g,
      (__attribute__((address_space(3))) void*)l, 16, 0, 0);
}

// ---------------- fused fp32 -> bf16 conversion (one launch) ----------------
struct Cvt7 {
  const float* src[7];
  ushort_t* dst[7];
  unsigned start[8];  // prefix, in float4 units
};
__global__ void cvt_all(Cvt7 a) {
  unsigned idx = blockIdx.x * blockDim.x + threadIdx.x;
  if (idx >= a.start[7]) return;
  int seg = 0;
#pragma unroll
  for (int j = 1; j < 7; j++) seg += (idx >= a.start[j]) ? 1 : 0;
  unsigned off = idx - a.start[seg];
  float4 v = ((const float4*)a.src[seg])[off];
  ((ushort4*)a.dst[seg])[off] = make_ushort4(f2b(v.x), f2b(v.y), f2b(v.z), f2b(v.w));
}

// ---------------- bf16 GEMM: C[M,N] = A[M,K] * B[N,K]^T ---------------------
// 128x128 tile, 256 thr (4 waves 2x2), wave 64x64 = 4x4 MFMA 16x16x32.
// BK=64 (half the barriers of BK=32), LDS 2x16KB.
// Swizzle: LDS row r chunk c (8 elem) holds global k-chunk c ^ (r&7); applied
// on the global side of global_load_lds (LDS side must stay lane-contiguous).
// Read side: chunk (h*4+fq) ^ (fr&7) -> any 8 sequential lanes hit 8 distinct
// 16B bank groups -> conflict-free (R2 measured 0 with the same technique).
// MODE 0: outB = bf16(acc)                         (QKV)
// MODE 1: outB = bf16(2*acc); outF = 2*acc + bias  (mid; outF seeds d_out)
// MODE 2: outB = bf16(relu(acc + bias[n]))         (MLP hidden)
// MODE 3: outF[idx] += acc                         (final; no split-K, RMW)
template <int MODE>
__launch_bounds__(256)
__global__ void gemm_bt(const ushort_t* __restrict__ A, const ushort_t* __restrict__ Bm,
                        int M, int N, int K,
                        ushort_t* __restrict__ outB, float* __restrict__ outF,
                        const float* __restrict__ bias) {
  __shared__ alignas(16) ushort_t As[128 * 64];
  __shared__ alignas(16) ushort_t Bs[128 * 64];
  const int tid = threadIdx.x;
  const int wave = tid >> 6, lane = tid & 63;
  const int wm = wave >> 1, wn = wave & 1;
  const int m0 = blockIdx.y * 128, n0 = blockIdx.x * 128;

  floatx4 acc[4][4];
#pragma unroll
  for (int i = 0; i < 4; i++)
#pragma unroll
    for (int j = 0; j < 4; j++) acc[i][j] = (floatx4){0.f, 0.f, 0.f, 0.f};

  // staging: call j (j=0..3) covers rows wave*32 + j*8 + (lane>>3), global
  // k-chunk (lane&7) ^ ((lane>>3)&7). 16B/lane, 8 async16 per wave per stage.
  const int srow = wave * 32 + (lane >> 3);
  const int scol = (((lane & 7) ^ ((lane >> 3) & 7)) * 8);
  const ushort_t* gA = A + (size_t)(m0 + srow) * K + scol;
  const ushort_t* gB = Bm + (size_t)(n0 + srow) * K + scol;
  ushort_t* lA = As + wave * 2048;
  ushort_t* lB = Bs + wave * 2048;

  const int fr = lane & 15, fq = lane >> 4;
  // fragment read: row R = (w*64 + mt*16 + fr), addr R*64 + ((h*4+fq)^(fr&7))*8
  const ushort_t* rdA = As + (wm * 64 + fr) * 64;
  const ushort_t* rdB = Bs + (wn * 64 + fr) * 64;
  const int sw = fr & 7;

  for (int k0 = 0; k0 < K; k0 += 64) {
#pragma unroll
    for (int j = 0; j < 4; j++) {
      async16(gA + (size_t)j * 8 * K, lA + j * 512);
      async16(gB + (size_t)j * 8 * K, lB + j * 512);
    }
    gA += 64; gB += 64;
    __syncthreads();
#pragma unroll
    for (int h = 0; h < 2; h++) {
      const int co = ((h * 4 + fq) ^ sw) * 8;
      short8 af[4], bfv[4];
#pragma unroll
      for (int mt = 0; mt < 4; mt++) af[mt] = *(const short8*)(rdA + mt * 16 * 64 + co);
#pragma unroll
      for (int nt = 0; nt < 4; nt++) bfv[nt] = *(const short8*)(rdB + nt * 16 * 64 + co);
#pragma unroll
      for (int mt = 0; mt < 4; mt++)
#pragma unroll
        for (int nt = 0; nt < 4; nt++)
          acc[mt][nt] = __builtin_amdgcn_mfma_f32_16x16x32_bf16(af[mt], bfv[nt], acc[mt][nt], 0, 0, 0);
    }
    __syncthreads();
  }

  const int crow = m0 + wm * 64 + (lane >> 4) * 4;
  const int ccol = n0 + wn * 64 + (lane & 15);
#pragma unroll
  for (int mt = 0; mt < 4; mt++)
#pragma unroll
    for (int nt = 0; nt < 4; nt++) {
      floatx4 a = acc[mt][nt];
#pragma unroll
      for (int r = 0; r < 4; r++) {
        const int gm = crow + mt * 16 + r;
        const int gn = ccol + nt * 16;
        const size_t idx = (size_t)gm * N + gn;
        float v = a[r];
        if constexpr (MODE == 0) {
          outB[idx] = f2b(v);
        } else if constexpr (MODE == 1) {
          float t = 2.f * v;
          outB[idx] = f2b(t);
          outF[idx] = t + bias[gn];
        } else if constexpr (MODE == 2) {
          float t = v + bias[gn];
          outB[idx] = f2b(t > 0.f ? t : 0.f);
        } else {
          outF[idx] += v;  // single owner per element; out pre-seeded by MODE1
        }
      }
    }
}

// ---------------- attention (degenerate mask -> diag + suffix sum) ----------
// z[q] = (e_q*v[q] + sum_{p>q} v[p]) / (e_q + (S-1-q)), e_q = exp(q.k/8)
__launch_bounds__(256)
__global__ void attn1(const ushort_t* __restrict__ qkv,
                      float* __restrict__ eG, float* __restrict__ psumG) {
  const int c = blockIdx.x & 31;
  const int i = (blockIdx.x >> 5) & 15;
  const int b = blockIdx.x >> 9;
  const int t = threadIdx.x, wave = t >> 6, h = t & 63;
  const size_t rowbase = (size_t)b * 2048 * 3072;
  float vacc = 0.f;
#pragma unroll 4
  for (int r = 0; r < 16; r++) {
    const int s = c * 64 + wave * 16 + r;
    const size_t rb = rowbase + (size_t)s * 3072 + i * 64 + h;
    float q = b2f(qkv[rb]);
    float k = b2f(qkv[rb + 1024]);
    float v = b2f(qkv[rb + 2048]);
    float d = q * k;
#pragma unroll
    for (int off = 32; off > 0; off >>= 1) d += __shfl_xor(d, off, 64);
    if (h == 0) eG[((size_t)(b * 16 + i)) * 2048 + s] = __expf(d * 0.125f);
    vacc += v;
  }
  __shared__ float vs[4][64];
  vs[wave][h] = vacc;
  __syncthreads();
  if (t < 64)
    psumG[(((size_t)(b * 16 + i)) * 32 + c) * 64 + t] =
        vs[0][t] + vs[1][t] + vs[2][t] + vs[3][t];
}

// Pass 2: 256 blocks x 256 thr; each wave owns one 64-s chunk. Loads batched
// 16-deep (independent of the serial `run` chain) for latency hiding.
__launch_bounds__(256)
__global__ void attn2(const ushort_t* __restrict__ qkv,
                      const float* __restrict__ eG, const float* __restrict__ psumG,
                      ushort_t* __restrict__ Z) {
  const int wave = threadIdx.x >> 6, h = threadIdx.x & 63;
  const int c = (blockIdx.x & 7) * 4 + wave;
  const int i = (blockIdx.x >> 3) & 15;
  const int b = blockIdx.x >> 7;
  const size_t rowbase = (size_t)b * 2048 * 3072;
  const size_t pbase = ((size_t)(b * 16 + i)) * 32;
  float run = 0.f;
#pragma unroll 8
  for (int cc = c + 1; cc < 32; cc++) run += psumG[(pbase + cc) * 64 + h];
  const size_t ebase = ((size_t)(b * 16 + i)) * 2048;
  for (int t4 = 3; t4 >= 0; t4--) {
    float vv[16], ee[16];
#pragma unroll
    for (int j = 0; j < 16; j++) {
      const int s = c * 64 + t4 * 16 + j;
      vv[j] = b2f(qkv[rowbase + (size_t)s * 3072 + 2048 + i * 64 + h]);
      ee[j] = eG[ebase + s];
    }
#pragma unroll
    for (int j = 15; j >= 0; j--) {
      const int s = c * 64 + t4 * 16 + j;
      float z = (ee[j] * vv[j] + run) / (ee[j] + (float)(2047 - s));
      Z[((size_t)b * 2048 + s) * 1024 + i * 64 + h] = f2b(z);
      run += vv[j];
    }
  }
}

// ---------------- launch ----------------------------------------------------
extern "C" void kernel_launch(void* const* d_in, const int* in_sizes, int n_in,
                              void* d_out, int out_size, void* d_ws, size_t ws_size,
                              hipStream_t stream) {
  const float* x     = (const float*)d_in[0];
  const float* W_Q   = (const float*)d_in[1];
  const float* W_K   = (const float*)d_in[2];
  const float* W_V   = (const float*)d_in[3];
  const float* W_O   = (const float*)d_in[4];
  const float* W_in  = (const float*)d_in[5];
  const float* b_in  = (const float*)d_in[6];
  const float* W_out = (const float*)d_in[7];
  const float* b_out = (const float*)d_in[8];
  float* out = (float*)d_out;

  char* base = (char*)d_ws;
  const size_t MB = 1048576;
  ushort_t* Xb    = (ushort_t*)(base + 0 * MB);    // 8 MB
  ushort_t* Wqkv  = (ushort_t*)(base + 8 * MB);    // 6 MB
  ushort_t* WOb   = (ushort_t*)(base + 14 * MB);   // 2 MB
  ushort_t* Z     = (ushort_t*)(base + 16 * MB);   // 8 MB
  ushort_t* QKV   = (ushort_t*)(base + 24 * MB);   // 24 MB
  ushort_t* midb  = (ushort_t*)(base + 48 * MB);   // 8 MB
  ushort_t* Winb  = (ushort_t*)(base + 56 * MB);   // 8 MB
  ushort_t* Woutb = (ushort_t*)(base + 64 * MB);   // 8 MB
  ushort_t* Hb    = (ushort_t*)(base + 72 * MB);   // 32 MB
  float*    eG    = (float*)(base + 104 * MB);           // 256 KB
  float*    psumG = (float*)(base + 104 * MB + 262144);  // 256 KB

  Cvt7 ca;
  ca.src[0] = x;     ca.dst[0] = Xb;
  ca.src[1] = W_Q;   ca.dst[1] = Wqkv;
  ca.src[2] = W_K;   ca.dst[2] = Wqkv + 1048576;
  ca.src[3] = W_V;   ca.dst[3] = Wqkv + 2097152;
  ca.src[4] = W_O;   ca.dst[4] = WOb;
  ca.src[5] = W_in;  ca.dst[5] = Winb;
  ca.src[6] = W_out; ca.dst[6] = Woutb;
  unsigned n4s[7] = {1048576, 262144, 262144, 262144, 262144, 1048576, 1048576};
  unsigned acc4 = 0;
  for (int j = 0; j < 7; j++) { ca.start[j] = acc4; acc4 += n4s[j]; }
  ca.start[7] = acc4;
  cvt_all<<<dim3((acc4 + 255) / 256), dim3(256), 0, stream>>>(ca);

  // QKV = X * Wqkv^T   [4096, 3072]
  gemm_bt<0><<<dim3(24, 32), 256, 0, stream>>>(Xb, Wqkv, 4096, 3072, 1024,
                                               QKV, nullptr, nullptr);
  // attention -> Z [4096, 1024] bf16
  attn1<<<dim3(1024), 256, 0, stream>>>(QKV, eG, psumG);
  attn2<<<dim3(256), 256, 0, stream>>>(QKV, eG, psumG, Z);
  // mid = 2*(Z*W_O^T): midb = bf16(mid), out seeded with mid + b_out
  gemm_bt<1><<<dim3(8, 32), 256, 0, stream>>>(Z, WOb, 4096, 1024, 1024,
                                              midb, out, b_out);
  // H = relu(mid * W_in^T + b_in) [4096, 4096]
  gemm_bt<2><<<dim3(32, 32), 256, 0, stream>>>(midb, Winb, 4096, 4096, 1024,
                                               Hb, nullptr, b_in);
  // out += H * W_out^T  (no split-K; plain per-element RMW)
  gemm_bt<3><<<dim3(8, 32), 256, 0, stream>>>(Hb, Woutb, 4096, 1024, 4096,
                                              nullptr, out, b_out);
}